// Round 1
// baseline (4195.748 us; speedup 1.0000x reference)
//
#include <hip/hip_runtime.h>
#include <math.h>

#define NNODES   80000
#define IN_DIM   8
#define HID      128
#define HEADS    8
#define KH       16
#define NEDGE    1280000
#define NETOT    (NEDGE + NNODES)
#define NEGS     0.2f
#define EPSBN    1e-5f
#define BATCH    8
#define PERB     10000

__device__ __forceinline__ float lrelu(float v) { return v >= 0.f ? v : NEGS * v; }

__device__ __forceinline__ void edge_sd(const int* __restrict__ ei, int e, int& s, int& d) {
  if (e < NEDGE) { s = ei[e]; d = ei[NEDGE + e]; }
  else           { s = e - NEDGE; d = s; }
}

// float atomic max via int/uint ordering trick (works for all finite floats, -inf init)
__device__ __forceinline__ void atomicMaxF(float* addr, float v) {
  if (v >= 0.f) atomicMax((int*)addr, __float_as_int(v));
  else          atomicMin((unsigned int*)addr, __float_as_uint(v));
}

// ---------- layer GEMMs ----------
// h[n,c] = sum_k x[n,k] * W[c,k]   (x @ W.T)
__global__ void k_gemm_in(const float* __restrict__ x, const float* __restrict__ W,
                          float* __restrict__ h) {
  int total = NNODES * HID;
  for (int idx = blockIdx.x * blockDim.x + threadIdx.x; idx < total;
       idx += gridDim.x * blockDim.x) {
    int n = idx >> 7, c = idx & 127;
    const float4* xr = (const float4*)(x + (size_t)n * IN_DIM);
    const float4* wr = (const float4*)(W + (size_t)c * IN_DIM);
    float4 a0 = xr[0], a1 = xr[1], b0 = wr[0], b1 = wr[1];
    h[idx] = a0.x*b0.x + a0.y*b0.y + a0.z*b0.z + a0.w*b0.w
           + a1.x*b1.x + a1.y*b1.y + a1.z*b1.z + a1.w*b1.w;
  }
}

__global__ void k_gemm128(const float* __restrict__ x, const float* __restrict__ W,
                          float* __restrict__ h) {
  int total = NNODES * HID;
  for (int idx = blockIdx.x * blockDim.x + threadIdx.x; idx < total;
       idx += gridDim.x * blockDim.x) {
    int n = idx >> 7, c = idx & 127;
    const float4* xr = (const float4*)(x + (size_t)n * HID);
    const float4* wr = (const float4*)(W + (size_t)c * HID);
    float acc = 0.f;
#pragma unroll 8
    for (int k = 0; k < HID / 4; k++) {
      float4 a = xr[k], b = wr[k];
      acc += a.x*b.x + a.y*b.y + a.z*b.z + a.w*b.w;
    }
    h[idx] = acc;
  }
}

// aL[n,hd] = sum_c h[n,hd,c]*att[hd,c] ; aR uses att[hd, KH+c]
__global__ void k_att_node(const float* __restrict__ h, const float* __restrict__ att,
                           float* __restrict__ aL, float* __restrict__ aR) {
  __shared__ float satt[HEADS * 2 * KH];
  for (int i = threadIdx.x; i < HEADS * 2 * KH; i += blockDim.x) satt[i] = att[i];
  __syncthreads();
  int total = NNODES * HEADS;
  for (int idx = blockIdx.x * blockDim.x + threadIdx.x; idx < total;
       idx += gridDim.x * blockDim.x) {
    int n = idx >> 3, hd = idx & 7;
    const float* hp  = h + (size_t)n * HID + hd * KH;
    const float* aLw = satt + hd * 2 * KH;
    const float* aRw = aLw + KH;
    float sl = 0.f, sr = 0.f;
#pragma unroll
    for (int c = 0; c < KH; c++) { float v = hp[c]; sl += v * aLw[c]; sr += v * aRw[c]; }
    aL[idx] = sl; aR[idx] = sr;
  }
}

__global__ void k_fill_neginf(float* __restrict__ a, int n) {
  for (int i = blockIdx.x * blockDim.x + threadIdx.x; i < n; i += gridDim.x * blockDim.x)
    a[i] = -INFINITY;
}

// pass 1: segment max over src
__global__ void k_edge_max(const int* __restrict__ ei, const float* __restrict__ aL,
                           const float* __restrict__ aR, float* __restrict__ amax) {
  int total = NETOT * HEADS;
  for (int idx = blockIdx.x * blockDim.x + threadIdx.x; idx < total;
       idx += gridDim.x * blockDim.x) {
    int e = idx >> 3, hd = idx & 7;
    int s, d; edge_sd(ei, e, s, d);
    float a = lrelu(aL[d * HEADS + hd] + aR[s * HEADS + hd]);
    atomicMaxF(&amax[s * HEADS + hd], a);
  }
}

// pass 2: segment sum of exp
__global__ void k_edge_den(const int* __restrict__ ei, const float* __restrict__ aL,
                           const float* __restrict__ aR, const float* __restrict__ amax,
                           float* __restrict__ den) {
  int total = NETOT * HEADS;
  for (int idx = blockIdx.x * blockDim.x + threadIdx.x; idx < total;
       idx += gridDim.x * blockDim.x) {
    int e = idx >> 3, hd = idx & 7;
    int s, d; edge_sd(ei, e, s, d);
    float a = lrelu(aL[d * HEADS + hd] + aR[s * HEADS + hd]);
    float w = expf(a - amax[s * HEADS + hd]);
    atomicAdd(&den[s * HEADS + hd], w);
  }
}

// pass 3: normalize + scatter messages to dst (thread per edge-channel)
__global__ void k_edge_agg(const int* __restrict__ ei, const float* __restrict__ aL,
                           const float* __restrict__ aR, const float* __restrict__ amax,
                           const float* __restrict__ den, const float* __restrict__ h,
                           float* __restrict__ agg) {
  long long total = (long long)NETOT * HID;
  for (long long idx = (long long)blockIdx.x * blockDim.x + threadIdx.x; idx < total;
       idx += (long long)gridDim.x * blockDim.x) {
    int e = (int)(idx >> 7), c = (int)(idx & 127);
    int hd = c >> 4;
    int s, d; edge_sd(ei, e, s, d);
    int sh = s * HEADS + hd;
    float a = lrelu(aL[d * HEADS + hd] + aR[sh]);
    float alpha = expf(a - amax[sh]) / (den[sh] + 1e-16f);
    atomicAdd(&agg[(size_t)d * HID + c], alpha * h[(size_t)s * HID + c]);
  }
}

// bias + relu + BN statistics (thread = channel, block strides rows)
__global__ void k_bnstats(const float* __restrict__ agg, const float* __restrict__ bias,
                          float* __restrict__ y, double* __restrict__ bnsum,
                          double* __restrict__ bnsq) {
  int c = threadIdx.x;
  float b = bias[c];
  float s = 0.f, sq = 0.f;
  for (int n = blockIdx.x; n < NNODES; n += gridDim.x) {
    float v = agg[(size_t)n * HID + c] + b;
    v = v > 0.f ? v : 0.f;
    y[(size_t)n * HID + c] = v;
    s += v; sq += v * v;
  }
  atomicAdd(&bnsum[c], (double)s);
  atomicAdd(&bnsq[c], (double)sq);
}

__global__ void k_bnfinal(const double* __restrict__ bnsum, const double* __restrict__ bnsq,
                          const float* __restrict__ g, const float* __restrict__ be,
                          float* __restrict__ scale, float* __restrict__ shift) {
  int c = threadIdx.x;
  double mean = bnsum[c] / (double)NNODES;
  double var  = bnsq[c] / (double)NNODES - mean * mean;
  float rs = (float)(1.0 / sqrt(var + (double)EPSBN));
  float sc = g[c] * rs;
  scale[c] = sc;
  shift[c] = be[c] - (float)mean * sc;
}

__global__ void k_bnapply(const float* __restrict__ y, const float* __restrict__ scale,
                          const float* __restrict__ shift, float* __restrict__ xo) {
  int total = NNODES * HID;
  for (int idx = blockIdx.x * blockDim.x + threadIdx.x; idx < total;
       idx += gridDim.x * blockDim.x) {
    int c = idx & 127;
    xo[idx] = lrelu(y[idx] * scale[c] + shift[c]);
  }
}

// power-mean partial sums: grid (chunks, batch), 128 threads = channels
__global__ void k_pmean(const float* __restrict__ xf, const float* __restrict__ p_,
                        float* __restrict__ xgsum) {
  int b = blockIdx.y, c = threadIdx.x;
  float p = p_[0];
  int rows_per = (PERB + gridDim.x - 1) / gridDim.x;
  int r0 = blockIdx.x * rows_per;
  int r1 = r0 + rows_per; if (r1 > PERB) r1 = PERB;
  float acc = 0.f;
  for (int i = r0; i < r1; i++) {
    float v = xf[((size_t)b * PERB + i) * HID + c];
    v = fminf(fmaxf(v, 0.f), 100.f);
    acc += powf(v, p);
  }
  atomicAdd(&xgsum[b * HID + c], acc);
}

__global__ void k_head(const float* __restrict__ xgsum, const float* __restrict__ p_,
                       const float* __restrict__ Wg, const float* __restrict__ bg,
                       float* __restrict__ out) {
  __shared__ float sxg[HID];
  __shared__ float red[HID];
  int b = blockIdx.x, c = threadIdx.x;
  float p = p_[0];
  float m = xgsum[b * HID + c] / (float)PERB;
  m = fminf(fmaxf(m, 0.f), 100.f);
  sxg[c] = powf(m, 1.0f / p);
  __syncthreads();
  float l0 = 0.f, l1 = 0.f;
  for (int j = 0; j < 2; j++) {
    red[c] = sxg[c] * Wg[j * HID + c];
    __syncthreads();
    for (int off = 64; off > 0; off >>= 1) {
      if (c < off) red[c] += red[c + off];
      __syncthreads();
    }
    if (c == 0) { if (j == 0) l0 = red[0] + bg[0]; else l1 = red[0] + bg[1]; }
    __syncthreads();
  }
  if (c == 0) {
    out[b * 2 + 0] = l0;
    out[b * 2 + 1] = l1;
    out[2 * BATCH + b] = (l1 > l0) ? 1.0f : 0.0f;   // argmax, first-max tie -> 0
  }
}

extern "C" void kernel_launch(void* const* d_in, const int* in_sizes, int n_in,
                              void* d_out, int out_size, void* d_ws, size_t ws_size,
                              hipStream_t stream) {
  (void)in_sizes; (void)n_in; (void)out_size; (void)ws_size;
  const float* x    = (const float*)d_in[0];
  const int*   ei   = (const int*)d_in[1];
  const float* Wl[3]   = { (const float*)d_in[2],  (const float*)d_in[7],  (const float*)d_in[12] };
  const float* attl[3] = { (const float*)d_in[3],  (const float*)d_in[8],  (const float*)d_in[13] };
  const float* bl[3]   = { (const float*)d_in[4],  (const float*)d_in[9],  (const float*)d_in[14] };
  const float* gl[3]   = { (const float*)d_in[5],  (const float*)d_in[10], (const float*)d_in[15] };
  const float* bel[3]  = { (const float*)d_in[6],  (const float*)d_in[11], (const float*)d_in[16] };
  const float* p    = (const float*)d_in[17];
  const float* Wg   = (const float*)d_in[18];
  const float* bg   = (const float*)d_in[19];
  float* out = (float*)d_out;

  float* ws   = (float*)d_ws;
  float* h    = ws;                                  // N*128
  float* agg  = h    + (size_t)NNODES * HID;         // N*128
  float* xbuf = agg  + (size_t)NNODES * HID;         // N*128
  float* aL   = xbuf + (size_t)NNODES * HID;         // N*8
  float* aR   = aL   + (size_t)NNODES * HEADS;
  float* amax = aR   + (size_t)NNODES * HEADS;
  float* den  = amax + (size_t)NNODES * HEADS;
  double* bnsum = (double*)(den + (size_t)NNODES * HEADS);   // byte offset 133,120,000 (8-aligned)
  double* bnsq  = bnsum + HID;
  float* scale  = (float*)(bnsq + HID);
  float* shift  = scale + HID;
  float* xgsum  = shift + HID;                       // 8*128

  for (int layer = 0; layer < 3; layer++) {
    const float* xin = (layer == 0) ? x : xbuf;
    if (layer == 0) k_gemm_in<<<4096, 256, 0, stream>>>(xin, Wl[0], h);
    else            k_gemm128<<<4096, 256, 0, stream>>>(xin, Wl[layer], h);

    k_att_node<<<2500, 256, 0, stream>>>(h, attl[layer], aL, aR);

    hipMemsetAsync(agg, 0, sizeof(float) * (size_t)NNODES * HID, stream);
    hipMemsetAsync(den, 0, sizeof(float) * (size_t)NNODES * HEADS, stream);
    k_fill_neginf<<<2500, 256, 0, stream>>>(amax, NNODES * HEADS);

    k_edge_max<<<4096, 256, 0, stream>>>(ei, aL, aR, amax);
    k_edge_den<<<4096, 256, 0, stream>>>(ei, aL, aR, amax, den);
    k_edge_agg<<<8192, 256, 0, stream>>>(ei, aL, aR, amax, den, h, agg);

    hipMemsetAsync(bnsum, 0, sizeof(double) * HID * 2, stream);
    k_bnstats<<<1024, 128, 0, stream>>>(agg, bl[layer], h, bnsum, bnsq);
    k_bnfinal<<<1, 128, 0, stream>>>(bnsum, bnsq, gl[layer], bel[layer], scale, shift);
    k_bnapply<<<4096, 256, 0, stream>>>(h, scale, shift, xbuf);
  }

  hipMemsetAsync(xgsum, 0, sizeof(float) * BATCH * HID, stream);
  k_pmean<<<dim3(32, BATCH), 128, 0, stream>>>(xbuf, p, xgsum);
  k_head<<<BATCH, 128, 0, stream>>>(xgsum, p, Wg, bg, out);
}

// Round 2
// 2959.564 us; speedup vs baseline: 1.4177x; 1.4177x over previous
//
#include <hip/hip_runtime.h>
#include <math.h>

#define NNODES   80000
#define IN_DIM   8
#define HID      128
#define HEADS    8
#define KH       16
#define NEDGE    1280000
#define NETOT    (NEDGE + NNODES)
#define NEGS     0.2f
#define EPSBN    1e-5f
#define BATCH    8
#define PERB     10000

__device__ __forceinline__ float lrelu(float v) { return v >= 0.f ? v : NEGS * v; }

__device__ __forceinline__ void edge_sd(const int* __restrict__ ei, int e, int& s, int& d) {
  if (e < NEDGE) { s = ei[e]; d = ei[NEDGE + e]; }
  else           { s = e - NEDGE; d = s; }
}

__device__ __forceinline__ void atomicMaxF(float* addr, float v) {
  if (v >= 0.f) atomicMax((int*)addr, __float_as_int(v));
  else          atomicMin((unsigned int*)addr, __float_as_uint(v));
}

// ---------- layer-1 GEMM (K=8): W1 held in registers, grid-stride nodes ----------
__global__ void k_gemm_in(const float* __restrict__ x, const float* __restrict__ W,
                          float* __restrict__ h) {
  int tid = blockIdx.x * blockDim.x + threadIdx.x;
  int tx = tid & 15;          // channel group: c0 = tx*8
  int c0 = tx * 8;
  // W slice for my 8 channels: w[j][k]
  float4 wv[16];
#pragma unroll
  for (int j = 0; j < 8; j++) {
    wv[j * 2 + 0] = *(const float4*)(W + (size_t)(c0 + j) * IN_DIM);
    wv[j * 2 + 1] = *(const float4*)(W + (size_t)(c0 + j) * IN_DIM + 4);
  }
  int stride = (gridDim.x * blockDim.x) >> 4;
  for (int n = tid >> 4; n < NNODES; n += stride) {
    float4 x0 = *(const float4*)(x + (size_t)n * IN_DIM);
    float4 x1 = *(const float4*)(x + (size_t)n * IN_DIM + 4);
    float o[8];
#pragma unroll
    for (int j = 0; j < 8; j++) {
      float4 a = wv[j * 2], b = wv[j * 2 + 1];
      o[j] = x0.x*a.x + x0.y*a.y + x0.z*a.z + x0.w*a.w
           + x1.x*b.x + x1.y*b.y + x1.z*b.z + x1.w*b.w;
    }
    float4* hp = (float4*)(h + (size_t)n * HID + c0);
    hp[0] = make_float4(o[0], o[1], o[2], o[3]);
    hp[1] = make_float4(o[4], o[5], o[6], o[7]);
  }
}

// ---------- 128x128 GEMM: 8 nodes x 8 channels per thread, W in LDS ----------
#define GB_NODES 128
__global__ __launch_bounds__(256, 2)
void k_gemm128_t(const float* __restrict__ x, const float* __restrict__ W,
                 float* __restrict__ h) {
  __shared__ float sw[HID][HID + 4];     // sw[k][c] = W[c][k]
  int tid = threadIdx.x;
  for (int idx = tid * 4; idx < HID * HID; idx += 256 * 4) {
    int c = idx >> 7, k = idx & 127;
    float4 w = *(const float4*)(W + (size_t)c * HID + k);
    sw[k + 0][c] = w.x; sw[k + 1][c] = w.y; sw[k + 2][c] = w.z; sw[k + 3][c] = w.w;
  }
  __syncthreads();
  int tx = tid & 15, ty = tid >> 4;
  int n0 = blockIdx.x * GB_NODES + ty * 8;
  int c0 = tx * 8;
  float acc[8][8];
#pragma unroll
  for (int i = 0; i < 8; i++)
#pragma unroll
    for (int j = 0; j < 8; j++) acc[i][j] = 0.f;

  const float* xp = x + (size_t)n0 * HID;
  for (int kk = 0; kk < HID; kk += 4) {
    float4 xv[8];
#pragma unroll
    for (int i = 0; i < 8; i++) xv[i] = *(const float4*)(xp + (size_t)i * HID + kk);
#pragma unroll
    for (int k4 = 0; k4 < 4; k4++) {
      float4 w0 = *(const float4*)&sw[kk + k4][c0];
      float4 w1 = *(const float4*)&sw[kk + k4][c0 + 4];
      float wj[8] = { w0.x, w0.y, w0.z, w0.w, w1.x, w1.y, w1.z, w1.w };
#pragma unroll
      for (int i = 0; i < 8; i++) {
        const float* xe = (const float*)&xv[i];
        float xs = xe[k4];
#pragma unroll
        for (int j = 0; j < 8; j++) acc[i][j] += xs * wj[j];
      }
    }
  }
#pragma unroll
  for (int i = 0; i < 8; i++) {
    float4* hp = (float4*)(h + (size_t)(n0 + i) * HID + c0);
    hp[0] = make_float4(acc[i][0], acc[i][1], acc[i][2], acc[i][3]);
    hp[1] = make_float4(acc[i][4], acc[i][5], acc[i][6], acc[i][7]);
  }
}

// aL[n,hd] = sum_c h[n,hd,c]*att[hd,c] ; aR uses att[hd, KH+c]
__global__ void k_att_node(const float* __restrict__ h, const float* __restrict__ att,
                           float* __restrict__ aL, float* __restrict__ aR) {
  __shared__ float satt[HEADS * 2 * KH];
  for (int i = threadIdx.x; i < HEADS * 2 * KH; i += blockDim.x) satt[i] = att[i];
  __syncthreads();
  int total = NNODES * HEADS;
  for (int idx = blockIdx.x * blockDim.x + threadIdx.x; idx < total;
       idx += gridDim.x * blockDim.x) {
    int n = idx >> 3, hd = idx & 7;
    const float* hp  = h + (size_t)n * HID + hd * KH;
    const float* aLw = satt + hd * 2 * KH;
    const float* aRw = aLw + KH;
    float sl = 0.f, sr = 0.f;
#pragma unroll
    for (int c = 0; c < KH; c++) { float v = hp[c]; sl += v * aLw[c]; sr += v * aRw[c]; }
    aL[idx] = sl; aR[idx] = sr;
  }
}

__global__ void k_fill_neginf(float* __restrict__ a, int n) {
  for (int i = blockIdx.x * blockDim.x + threadIdx.x; i < n; i += gridDim.x * blockDim.x)
    a[i] = -INFINITY;
}

// pass 1: compute a per edge, store (real edges), segment max over src
__global__ void k_edge_max(const int* __restrict__ ei, const float* __restrict__ aL,
                           const float* __restrict__ aR, float* __restrict__ amax,
                           float* __restrict__ ae) {
  int total = NETOT * HEADS;
  for (int idx = blockIdx.x * blockDim.x + threadIdx.x; idx < total;
       idx += gridDim.x * blockDim.x) {
    int e = idx >> 3, hd = idx & 7;
    int s, d; edge_sd(ei, e, s, d);
    float a = lrelu(aL[d * HEADS + hd] + aR[s * HEADS + hd]);
    if (e < NEDGE) ae[idx] = a;
    atomicMaxF(&amax[s * HEADS + hd], a);
  }
}

// pass 2: segment sum of exp
__global__ void k_edge_den(const int* __restrict__ ei, const float* __restrict__ aL,
                           const float* __restrict__ aR, const float* __restrict__ amax,
                           float* __restrict__ den, const float* __restrict__ ae) {
  int total = NETOT * HEADS;
  for (int idx = blockIdx.x * blockDim.x + threadIdx.x; idx < total;
       idx += gridDim.x * blockDim.x) {
    int e = idx >> 3, hd = idx & 7;
    int s, d; edge_sd(ei, e, s, d);
    float a;
    if (e < NEDGE) a = ae[idx];
    else { int sh = s * HEADS + hd; a = lrelu(aL[sh] + aR[sh]); }
    float w = expf(a - amax[s * HEADS + hd]);
    atomicAdd(&den[s * HEADS + hd], w);
  }
}

// pass 2.5: finalize alpha for real edges (in place in ae)
__global__ void k_edge_alpha(const int* __restrict__ ei, const float* __restrict__ amax,
                             const float* __restrict__ den, float* __restrict__ ae) {
  int total = NEDGE * HEADS;
  for (int idx = blockIdx.x * blockDim.x + threadIdx.x; idx < total;
       idx += gridDim.x * blockDim.x) {
    int e = idx >> 3, hd = idx & 7;
    int s = ei[e];
    int sh = s * HEADS + hd;
    ae[idx] = expf(ae[idx] - amax[sh]) / (den[sh] + 1e-16f);
  }
}

// pass 3: scatter alpha * h[src] to dst
__global__ void k_edge_agg(const int* __restrict__ ei, const float* __restrict__ aL,
                           const float* __restrict__ aR, const float* __restrict__ amax,
                           const float* __restrict__ den, const float* __restrict__ ae,
                           const float* __restrict__ h, float* __restrict__ agg) {
  long long total = (long long)NETOT * HID;
  for (long long idx = (long long)blockIdx.x * blockDim.x + threadIdx.x; idx < total;
       idx += (long long)gridDim.x * blockDim.x) {
    int e = (int)(idx >> 7), c = (int)(idx & 127);
    int hd = c >> 4;
    int s, d; edge_sd(ei, e, s, d);
    float alpha;
    if (e < NEDGE) alpha = ae[e * HEADS + hd];
    else {
      int sh = s * HEADS + hd;
      float a = lrelu(aL[sh] + aR[sh]);
      alpha = expf(a - amax[sh]) / (den[sh] + 1e-16f);
    }
    atomicAdd(&agg[(size_t)d * HID + c], alpha * h[(size_t)s * HID + c]);
  }
}

// bias + relu + BN statistics (thread = channel, block strides rows)
__global__ void k_bnstats(const float* __restrict__ agg, const float* __restrict__ bias,
                          float* __restrict__ y, double* __restrict__ bnsum,
                          double* __restrict__ bnsq) {
  int c = threadIdx.x;
  float b = bias[c];
  float s = 0.f, sq = 0.f;
  for (int n = blockIdx.x; n < NNODES; n += gridDim.x) {
    float v = agg[(size_t)n * HID + c] + b;
    v = v > 0.f ? v : 0.f;
    y[(size_t)n * HID + c] = v;
    s += v; sq += v * v;
  }
  atomicAdd(&bnsum[c], (double)s);
  atomicAdd(&bnsq[c], (double)sq);
}

__global__ void k_bnfinal(const double* __restrict__ bnsum, const double* __restrict__ bnsq,
                          const float* __restrict__ g, const float* __restrict__ be,
                          float* __restrict__ scale, float* __restrict__ shift) {
  int c = threadIdx.x;
  double mean = bnsum[c] / (double)NNODES;
  double var  = bnsq[c] / (double)NNODES - mean * mean;
  float rs = (float)(1.0 / sqrt(var + (double)EPSBN));
  float sc = g[c] * rs;
  scale[c] = sc;
  shift[c] = be[c] - (float)mean * sc;
}

__global__ void k_bnapply(const float* __restrict__ y, const float* __restrict__ scale,
                          const float* __restrict__ shift, float* __restrict__ xo) {
  int total = NNODES * HID;
  for (int idx = blockIdx.x * blockDim.x + threadIdx.x; idx < total;
       idx += gridDim.x * blockDim.x) {
    int c = idx & 127;
    xo[idx] = lrelu(y[idx] * scale[c] + shift[c]);
  }
}

// power-mean partial sums
__global__ void k_pmean(const float* __restrict__ xf, const float* __restrict__ p_,
                        float* __restrict__ xgsum) {
  int b = blockIdx.y, c = threadIdx.x;
  float p = p_[0];
  int rows_per = (PERB + gridDim.x - 1) / gridDim.x;
  int r0 = blockIdx.x * rows_per;
  int r1 = r0 + rows_per; if (r1 > PERB) r1 = PERB;
  float acc = 0.f;
  for (int i = r0; i < r1; i++) {
    float v = xf[((size_t)b * PERB + i) * HID + c];
    v = fminf(fmaxf(v, 0.f), 100.f);
    acc += powf(v, p);
  }
  atomicAdd(&xgsum[b * HID + c], acc);
}

__global__ void k_head(const float* __restrict__ xgsum, const float* __restrict__ p_,
                       const float* __restrict__ Wg, const float* __restrict__ bg,
                       float* __restrict__ out) {
  __shared__ float sxg[HID];
  __shared__ float red[HID];
  int b = blockIdx.x, c = threadIdx.x;
  float p = p_[0];
  float m = xgsum[b * HID + c] / (float)PERB;
  m = fminf(fmaxf(m, 0.f), 100.f);
  sxg[c] = powf(m, 1.0f / p);
  __syncthreads();
  float l0 = 0.f, l1 = 0.f;
  for (int j = 0; j < 2; j++) {
    red[c] = sxg[c] * Wg[j * HID + c];
    __syncthreads();
    for (int off = 64; off > 0; off >>= 1) {
      if (c < off) red[c] += red[c + off];
      __syncthreads();
    }
    if (c == 0) { if (j == 0) l0 = red[0] + bg[0]; else l1 = red[0] + bg[1]; }
    __syncthreads();
  }
  if (c == 0) {
    out[b * 2 + 0] = l0;
    out[b * 2 + 1] = l1;
    out[2 * BATCH + b] = (l1 > l0) ? 1.0f : 0.0f;
  }
}

extern "C" void kernel_launch(void* const* d_in, const int* in_sizes, int n_in,
                              void* d_out, int out_size, void* d_ws, size_t ws_size,
                              hipStream_t stream) {
  (void)in_sizes; (void)n_in; (void)out_size; (void)ws_size;
  const float* x    = (const float*)d_in[0];
  const int*   ei   = (const int*)d_in[1];
  const float* Wl[3]   = { (const float*)d_in[2],  (const float*)d_in[7],  (const float*)d_in[12] };
  const float* attl[3] = { (const float*)d_in[3],  (const float*)d_in[8],  (const float*)d_in[13] };
  const float* bl[3]   = { (const float*)d_in[4],  (const float*)d_in[9],  (const float*)d_in[14] };
  const float* gl[3]   = { (const float*)d_in[5],  (const float*)d_in[10], (const float*)d_in[15] };
  const float* bel[3]  = { (const float*)d_in[6],  (const float*)d_in[11], (const float*)d_in[16] };
  const float* p    = (const float*)d_in[17];
  const float* Wg   = (const float*)d_in[18];
  const float* bg   = (const float*)d_in[19];
  float* out = (float*)d_out;

  float* ws   = (float*)d_ws;
  float* h    = ws;                                  // N*128
  float* agg  = h    + (size_t)NNODES * HID;         // N*128
  float* xbuf = agg  + (size_t)NNODES * HID;         // N*128 (aliased as ae during edge phase)
  float* aL   = xbuf + (size_t)NNODES * HID;         // N*8
  float* aR   = aL   + (size_t)NNODES * HEADS;
  float* amax = aR   + (size_t)NNODES * HEADS;
  float* den  = amax + (size_t)NNODES * HEADS;
  double* bnsum = (double*)(den + (size_t)NNODES * HEADS);
  double* bnsq  = bnsum + HID;
  float* scale  = (float*)(bnsq + HID);
  float* shift  = scale + HID;
  float* xgsum  = shift + HID;                       // 8*128
  float* ae = xbuf;                                  // NEDGE*8 = N*128 exactly

  for (int layer = 0; layer < 3; layer++) {
    const float* xin = (layer == 0) ? x : xbuf;
    if (layer == 0) k_gemm_in<<<2048, 256, 0, stream>>>(xin, Wl[0], h);
    else            k_gemm128_t<<<NNODES / GB_NODES, 256, 0, stream>>>(xin, Wl[layer], h);

    k_att_node<<<2500, 256, 0, stream>>>(h, attl[layer], aL, aR);

    hipMemsetAsync(agg, 0, sizeof(float) * (size_t)NNODES * HID, stream);
    hipMemsetAsync(den, 0, sizeof(float) * (size_t)NNODES * HEADS, stream);
    k_fill_neginf<<<2500, 256, 0, stream>>>(amax, NNODES * HEADS);

    k_edge_max<<<4096, 256, 0, stream>>>(ei, aL, aR, amax, ae);
    k_edge_den<<<4096, 256, 0, stream>>>(ei, aL, aR, amax, den, ae);
    k_edge_alpha<<<4096, 256, 0, stream>>>(ei, amax, den, ae);
    k_edge_agg<<<8192, 256, 0, stream>>>(ei, aL, aR, amax, den, ae, h, agg);

    hipMemsetAsync(bnsum, 0, sizeof(double) * HID * 2, stream);
    k_bnstats<<<1024, 128, 0, stream>>>(agg, bl[layer], h, bnsum, bnsq);
    k_bnfinal<<<1, 128, 0, stream>>>(bnsum, bnsq, gl[layer], bel[layer], scale, shift);
    k_bnapply<<<4096, 256, 0, stream>>>(h, scale, shift, xbuf);
  }

  hipMemsetAsync(xgsum, 0, sizeof(float) * BATCH * HID, stream);
  k_pmean<<<dim3(32, BATCH), 128, 0, stream>>>(xbuf, p, xgsum);
  k_head<<<BATCH, 128, 0, stream>>>(xgsum, p, Wg, bg, out);
}